// Round 1
// baseline (591.397 us; speedup 1.0000x reference)
//
#include <hip/hip_runtime.h>
#include <math.h>

#define BB 256
#define PP 16
#define LL 4
#define EE 128
#define CC1 512
#define CC2 256

// ---------------------------------------------------------------------------
// Kernel 1: per-path gathered linear chain.
// grid = B*P = 4096 blocks, 256 threads.
// threads 0..127 -> x output rows, 128..255 -> y output rows.
// Each lane streams its W row (float4, L1-sequential); input vec broadcast
// from LDS. x and y lanes read the same W rows -> L1 reuse.
// ---------------------------------------------------------------------------
__global__ __launch_bounds__(256) void path_kernel(
    const int* __restrict__ start_ids, const int* __restrict__ end_ids,
    const int* __restrict__ module_ids,
    const float* __restrict__ embed, const float* __restrict__ W,
    const float* __restrict__ bvec,
    float* __restrict__ feat_ws)
{
    const int bp = blockIdx.x;            // path index 0..4095
    const int t  = threadIdx.x;           // 0..255

    __shared__ float bufx[2][EE];
    __shared__ float bufy[2][EE];

    // Load endpoint embeddings (coalesced 512B rows).
    const int sid = start_ids[bp];
    const int eid = end_ids[bp];
    if (t < EE) bufx[0][t]      = embed[(size_t)sid * EE + t];
    else        bufy[0][t - EE] = embed[(size_t)eid * EE + (t - EE)];
    __syncthreads();

    const int o = t & (EE - 1);
    int cur = 0;
    for (int l = 0; l < LL; ++l) {
        const int mid = module_ids[bp * LL + l];
        const float*  vin  = (t < EE) ? bufx[cur] : bufy[cur];   // wave-uniform
        const float4* v4   = (const float4*)vin;
        const float4* wrow = (const float4*)(W + ((size_t)mid * EE + o) * EE);

        float acc = bvec[(size_t)mid * EE + o];
        #pragma unroll 8
        for (int k = 0; k < EE / 4; ++k) {
            const float4 w = wrow[k];
            const float4 v = v4[k];
            acc = fmaf(w.x, v.x, acc);
            acc = fmaf(w.y, v.y, acc);
            acc = fmaf(w.z, v.z, acc);
            acc = fmaf(w.w, v.w, acc);
        }
        // write to the other buffer; single barrier per step is sufficient
        if (t < EE) bufx[1 - cur][o] = acc;
        else        bufy[1 - cur][o] = acc;
        __syncthreads();
        cur = 1 - cur;
    }

    // feat = concat(x, y) -> workspace [B*P, 256]
    const float val = (t < EE) ? bufx[cur][t] : bufy[cur][t - EE];
    feat_ws[(size_t)bp * (2 * EE) + t] = val;
}

// ---------------------------------------------------------------------------
// Kernel 2: pooling + MLP. 32 blocks x 256 threads, 8 batch rows per block
// (weight rows reused across 8 batches).
// ---------------------------------------------------------------------------
__global__ __launch_bounds__(256) void mlp_kernel(
    const int* __restrict__ counts,
    const float* __restrict__ feat_ws,
    const float* __restrict__ W1, const float* __restrict__ b1,
    const float* __restrict__ W2, const float* __restrict__ b2,
    const float* __restrict__ W3, const float* __restrict__ b3,
    float* __restrict__ out)
{
    const int t  = threadIdx.x;      // 0..255
    const int b0 = blockIdx.x * 8;

    __shared__ float pooled[8][2 * EE];  // 8 KB
    __shared__ float h1s[8][CC1];        // 16 KB
    __shared__ float h2s[8][CC2];        // 8 KB

    // ---- pooling: pooled[j][t] = sum_p c * feat / sum_p c ----
    for (int j = 0; j < 8; ++j) {
        const int b = b0 + j;
        float acc = 0.f, csum = 0.f;
        #pragma unroll
        for (int p = 0; p < PP; ++p) {
            const float c = (float)counts[b * PP + p];
            csum += c;
            acc = fmaf(c, feat_ws[(size_t)(b * PP + p) * (2 * EE) + t], acc);
        }
        pooled[j][t] = acc / csum;
    }
    __syncthreads();

    // ---- h1 = relu(pooled @ W1^T + b1): rows t and t+256 ----
    for (int rh = 0; rh < 2; ++rh) {
        const int r = t + rh * 256;
        float acc[8];
        const float bb = b1[r];
        #pragma unroll
        for (int j = 0; j < 8; ++j) acc[j] = bb;
        const float4* w4 = (const float4*)(W1 + (size_t)r * (2 * EE));
        for (int k = 0; k < (2 * EE) / 4; ++k) {
            const float4 w = w4[k];
            #pragma unroll
            for (int j = 0; j < 8; ++j) {
                const float4 v = ((const float4*)pooled[j])[k];
                acc[j] = fmaf(w.x, v.x, acc[j]);
                acc[j] = fmaf(w.y, v.y, acc[j]);
                acc[j] = fmaf(w.z, v.z, acc[j]);
                acc[j] = fmaf(w.w, v.w, acc[j]);
            }
        }
        #pragma unroll
        for (int j = 0; j < 8; ++j) h1s[j][r] = fmaxf(acc[j], 0.f);
    }
    __syncthreads();

    // ---- h2 = relu(h1 @ W2^T + b2): row t ----
    {
        const int r = t;
        float acc[8];
        const float bb = b2[r];
        #pragma unroll
        for (int j = 0; j < 8; ++j) acc[j] = bb;
        const float4* w4 = (const float4*)(W2 + (size_t)r * CC1);
        for (int k = 0; k < CC1 / 4; ++k) {
            const float4 w = w4[k];
            #pragma unroll
            for (int j = 0; j < 8; ++j) {
                const float4 v = ((const float4*)h1s[j])[k];
                acc[j] = fmaf(w.x, v.x, acc[j]);
                acc[j] = fmaf(w.y, v.y, acc[j]);
                acc[j] = fmaf(w.z, v.z, acc[j]);
                acc[j] = fmaf(w.w, v.w, acc[j]);
            }
        }
        #pragma unroll
        for (int j = 0; j < 8; ++j) h2s[j][r] = fmaxf(acc[j], 0.f);
    }
    __syncthreads();

    // ---- out = sigmoid(h2 @ W3^T + b3), 32 lanes per batch row ----
    const int j = t >> 5;
    const int k = t & 31;
    float partial = 0.f;
    #pragma unroll
    for (int m = 0; m < CC2; m += 32)
        partial = fmaf(W3[k + m], h2s[j][k + m], partial);
    #pragma unroll
    for (int s = 16; s >= 1; s >>= 1)
        partial += __shfl_down(partial, s, 32);
    if (k == 0)
        out[b0 + j] = 1.f / (1.f + expf(-(partial + b3[0])));
}

// ---------------------------------------------------------------------------
extern "C" void kernel_launch(void* const* d_in, const int* in_sizes, int n_in,
                              void* d_out, int out_size, void* d_ws, size_t ws_size,
                              hipStream_t stream)
{
    const int*   start_ids  = (const int*)d_in[0];
    const int*   end_ids    = (const int*)d_in[1];
    const int*   module_ids = (const int*)d_in[2];
    const int*   counts     = (const int*)d_in[3];
    const float* embed      = (const float*)d_in[4];
    const float* W          = (const float*)d_in[5];
    const float* bvec       = (const float*)d_in[6];
    const float* W1         = (const float*)d_in[7];
    const float* b1         = (const float*)d_in[8];
    const float* W2         = (const float*)d_in[9];
    const float* b2         = (const float*)d_in[10];
    const float* W3         = (const float*)d_in[11];
    const float* b3         = (const float*)d_in[12];

    float* out     = (float*)d_out;
    float* feat_ws = (float*)d_ws;   // B*P*256 floats = 4 MB

    path_kernel<<<BB * PP, 256, 0, stream>>>(
        start_ids, end_ids, module_ids, embed, W, bvec, feat_ws);

    mlp_kernel<<<BB / 8, 256, 0, stream>>>(
        counts, feat_ws, W1, b1, W2, b2, W3, b3, out);
}

// Round 3
// 451.831 us; speedup vs baseline: 1.3089x; 1.3089x over previous
//
#include <hip/hip_runtime.h>
#include <math.h>

#define BB 256
#define PP 16
#define LL 4
#define EE 128
#define NPATH (BB*PP)     // 4096
#define NMOD 512
#define CC1 512
#define CC2 256

// ---------------- workspace layout (fast path) ----------------
#define WS_STATE   0                              // [4096][2][128] f32 = 4 MB
#define WS_CNT     (NPATH*2*EE*4)                 // [4][512] int
#define WS_OFF     (WS_CNT  + LL*NMOD*4)
#define WS_CUR     (WS_OFF  + LL*NMOD*4)
#define WS_LISTS   (WS_CUR  + LL*NMOD*4)          // [4][4096] int
#define WS_POOLED  (WS_LISTS + LL*NPATH*4)        // [256][256] f32
#define WS_H1      (WS_POOLED + BB*2*EE*4)        // [256][512] f32
#define WS_H2      (WS_H1 + BB*CC1*4)             // [256][256] f32
#define WS_END     (WS_H2 + BB*CC2*4)             // ~5.09 MB

// NOTE: parameter names must not collide with float4 member names (.x/.y/.z/.w)
#define FMA4(A, S, Wv) do{ (A).x=fmaf((S),(Wv).x,(A).x); (A).y=fmaf((S),(Wv).y,(A).y); \
                           (A).z=fmaf((S),(Wv).z,(A).z); (A).w=fmaf((S),(Wv).w,(A).w);}while(0)

// ---------------- bucketing ----------------
__global__ __launch_bounds__(256) void k_zero(int* __restrict__ cnt) {
    cnt[blockIdx.x*256 + threadIdx.x] = 0;   // grid 8 -> 2048 entries
}

__global__ __launch_bounds__(256) void k_seed(
    const int* __restrict__ start_ids, const int* __restrict__ end_ids,
    const int* __restrict__ module_ids, const float* __restrict__ embed,
    float* __restrict__ state, int* __restrict__ cnt)
{
    const int bp = blockIdx.x, t = threadIdx.x;
    const int id = (t < EE) ? start_ids[bp] : end_ids[bp];
    state[(size_t)bp*256 + t] = embed[(size_t)id*EE + (t & (EE-1))];
    if (t < LL) atomicAdd(&cnt[t*NMOD + module_ids[bp*LL + t]], 1);
}

__global__ void k_scan(const int* __restrict__ cnt, int* __restrict__ off,
                       int* __restrict__ cur)
{   // grid 4 (one per step), block 512: exclusive prefix sum over 512 mids
    const int l = blockIdx.x, t = threadIdx.x;
    __shared__ int s[NMOD];
    const int c = cnt[l*NMOD + t];
    s[t] = c; __syncthreads();
    for (int d = 1; d < NMOD; d <<= 1) {
        const int v = (t >= d) ? s[t-d] : 0;
        __syncthreads();
        s[t] += v;
        __syncthreads();
    }
    const int excl = s[t] - c;
    off[l*NMOD + t] = excl;
    cur[l*NMOD + t] = excl;
}

__global__ __launch_bounds__(256) void k_scatter(
    const int* __restrict__ module_ids, int* __restrict__ cur,
    int* __restrict__ lists)
{   // grid 64: one thread per (path, step)
    const int gid = blockIdx.x*256 + threadIdx.x;   // = bp*4 + l
    const int bp = gid >> 2, l = gid & 3;
    const int m = module_ids[gid];
    const int pos = atomicAdd(&cur[l*NMOD + m], 1);
    lists[l*NPATH + pos] = bp;
}

// ---------------- grouped per-module matvec step ----------------
// One block per module id. W[m] staged (transposed) in LDS in two 64-col
// halves; path x/y vectors staged in a 32-row swizzled slab; in-place update.
__global__ __launch_bounds__(256) void k_step(
    const int l, const float* __restrict__ W, const float* __restrict__ bvec,
    const int* __restrict__ cnt, const int* __restrict__ off,
    const int* __restrict__ lists, float* __restrict__ state)
{
    __shared__ float Wt[128*64];   // [k][oc], 32 KB (one output half)
    __shared__ float vb[32*128];   // [row][k], chunk-swizzled, 16 KB
    const int m = blockIdx.x, t = threadIdx.x;
    const int n = cnt[l*NMOD + m];
    if (n == 0) return;
    const int* lst = lists + l*NPATH + off[l*NMOD + m];
    const int nr = 2*n;                // rows = (path, x|y)
    const int c = t & 15;              // 4 output cols per thread
    const int g = t >> 4;              // 2 rows per thread
    const float4* state4c = (const float4*)state;

    for (int base = 0; base < nr; base += 32) {
        __syncthreads();               // prior slab readers done with vb
        #pragma unroll
        for (int it = 0; it < 4; ++it) {
            const int flat = it*256 + t;
            const int row = flat >> 5, c4 = flat & 31;
            const int pc = c4 ^ ((row >> 1) & 3);     // bank swizzle
            float4 v = make_float4(0.f, 0.f, 0.f, 0.f);
            const int r = base + row;
            if (r < nr) {
                const int pv = lst[r >> 1]*2 + (r & 1);
                v = state4c[pv*32 + c4];
            }
            ((float4*)vb)[row*32 + pc] = v;
        }
        for (int ch = 0; ch < 2; ++ch) {
            __syncthreads();           // vb visible / prior Wt readers done
            {   // Wt[k][oc] = W[m][ch*64+oc][k]  (transpose during stage)
                const int oc = t & 63, kh = t >> 6;
                const float4* Wr = (const float4*)(W + ((size_t)m*128 + ch*64 + oc)*128);
                #pragma unroll
                for (int it = 0; it < 8; ++it) {
                    const int k0 = kh*32 + it*4;
                    const float4 wv = Wr[k0 >> 2];
                    Wt[(k0+0)*64 + oc] = wv.x;
                    Wt[(k0+1)*64 + oc] = wv.y;
                    Wt[(k0+2)*64 + oc] = wv.z;
                    Wt[(k0+3)*64 + oc] = wv.w;
                }
            }
            __syncthreads();
            float4 acc0 = make_float4(0,0,0,0), acc1 = make_float4(0,0,0,0);
            const int row0 = g*2, row1 = g*2 + 1;
            const int sw = g & 3;      // (row>>1)&3 for both rows
            #pragma unroll 4
            for (int k0 = 0; k0 < 128; k0 += 4) {
                const int q = k0 >> 2;
                const float4 w0 = ((const float4*)Wt)[(k0+0)*16 + c];
                const float4 w1 = ((const float4*)Wt)[(k0+1)*16 + c];
                const float4 w2 = ((const float4*)Wt)[(k0+2)*16 + c];
                const float4 w3 = ((const float4*)Wt)[(k0+3)*16 + c];
                const float4 va = ((const float4*)vb)[row0*32 + (q ^ sw)];
                const float4 vy = ((const float4*)vb)[row1*32 + (q ^ sw)];
                FMA4(acc0, va.x, w0); FMA4(acc0, va.y, w1);
                FMA4(acc0, va.z, w2); FMA4(acc0, va.w, w3);
                FMA4(acc1, vy.x, w0); FMA4(acc1, vy.y, w1);
                FMA4(acc1, vy.z, w2); FMA4(acc1, vy.w, w3);
            }
            const float4 bias4 = ((const float4*)(bvec + (size_t)m*128 + ch*64))[c];
            int r = base + row0;
            if (r < nr) {
                const int pv = lst[r >> 1]*2 + (r & 1);
                float4 o = make_float4(acc0.x + bias4.x, acc0.y + bias4.y,
                                       acc0.z + bias4.z, acc0.w + bias4.w);
                ((float4*)state)[pv*32 + ch*16 + c] = o;
            }
            r = base + row1;
            if (r < nr) {
                const int pv = lst[r >> 1]*2 + (r & 1);
                float4 o = make_float4(acc1.x + bias4.x, acc1.y + bias4.y,
                                       acc1.z + bias4.z, acc1.w + bias4.w);
                ((float4*)state)[pv*32 + ch*16 + c] = o;
            }
        }
    }
}

// ---------------- pooling + MLP ----------------
__global__ __launch_bounds__(256) void k_pool(
    const int* __restrict__ counts, const float* __restrict__ state,
    float* __restrict__ pooled)
{
    const int b = blockIdx.x, t = threadIdx.x;
    float acc = 0.f, cs = 0.f;
    #pragma unroll
    for (int p = 0; p < PP; ++p) {
        const float cc = (float)counts[b*PP + p];
        cs += cc;
        acc = fmaf(cc, state[((size_t)(b*PP + p))*256 + t], acc);
    }
    pooled[b*256 + t] = acc / cs;
}

__global__ __launch_bounds__(256) void k_h1(
    const float* __restrict__ pooled, const float* __restrict__ W1,
    const float* __restrict__ b1, float* __restrict__ h1)
{   // grid 128 = 32 batch-groups(8) x 4 col-groups(128)
    __shared__ float ps[8*256];
    const int t = threadIdx.x;
    const int bg = blockIdx.x >> 2, cg = blockIdx.x & 3;
    #pragma unroll
    for (int it = 0; it < 8; ++it) {
        const int flat = it*256 + t;
        ps[flat] = pooled[bg*8*256 + flat];
    }
    __syncthreads();
    const int col = cg*128 + (t & 127);
    const int h = t >> 7;              // 4 batches per thread
    const float4* w4 = (const float4*)(W1 + (size_t)col*256);
    const float4* ps4 = (const float4*)ps;
    float a0, a1, a2, a3; a0 = a1 = a2 = a3 = b1[col];
    for (int q = 0; q < 64; ++q) {
        const float4 wv = w4[q];
        const float4 v0 = ps4[(h*4+0)*64 + q];
        const float4 v1 = ps4[(h*4+1)*64 + q];
        const float4 v2 = ps4[(h*4+2)*64 + q];
        const float4 v3 = ps4[(h*4+3)*64 + q];
        a0 = fmaf(wv.x,v0.x, fmaf(wv.y,v0.y, fmaf(wv.z,v0.z, fmaf(wv.w,v0.w, a0))));
        a1 = fmaf(wv.x,v1.x, fmaf(wv.y,v1.y, fmaf(wv.z,v1.z, fmaf(wv.w,v1.w, a1))));
        a2 = fmaf(wv.x,v2.x, fmaf(wv.y,v2.y, fmaf(wv.z,v2.z, fmaf(wv.w,v2.w, a2))));
        a3 = fmaf(wv.x,v3.x, fmaf(wv.y,v3.y, fmaf(wv.z,v3.z, fmaf(wv.w,v3.w, a3))));
    }
    const int b0 = bg*8 + h*4;
    h1[(size_t)(b0+0)*CC1 + col] = fmaxf(a0, 0.f);
    h1[(size_t)(b0+1)*CC1 + col] = fmaxf(a1, 0.f);
    h1[(size_t)(b0+2)*CC1 + col] = fmaxf(a2, 0.f);
    h1[(size_t)(b0+3)*CC1 + col] = fmaxf(a3, 0.f);
}

__global__ __launch_bounds__(256) void k_h2(
    const float* __restrict__ h1, const float* __restrict__ W2,
    const float* __restrict__ b2, float* __restrict__ h2)
{   // grid 64 = 32 batch-groups(8) x 2 col-groups(128)
    __shared__ float hs[8*512];
    const int t = threadIdx.x;
    const int bg = blockIdx.x >> 1, cg = blockIdx.x & 1;
    #pragma unroll
    for (int it = 0; it < 16; ++it) {
        const int flat = it*256 + t;
        hs[flat] = h1[(size_t)bg*8*512 + flat];
    }
    __syncthreads();
    const int col = cg*128 + (t & 127);
    const int h = t >> 7;
    const float4* w4 = (const float4*)(W2 + (size_t)col*512);
    const float4* hs4 = (const float4*)hs;
    float a0, a1, a2, a3; a0 = a1 = a2 = a3 = b2[col];
    for (int q = 0; q < 128; ++q) {
        const float4 wv = w4[q];
        const float4 v0 = hs4[(h*4+0)*128 + q];
        const float4 v1 = hs4[(h*4+1)*128 + q];
        const float4 v2 = hs4[(h*4+2)*128 + q];
        const float4 v3 = hs4[(h*4+3)*128 + q];
        a0 = fmaf(wv.x,v0.x, fmaf(wv.y,v0.y, fmaf(wv.z,v0.z, fmaf(wv.w,v0.w, a0))));
        a1 = fmaf(wv.x,v1.x, fmaf(wv.y,v1.y, fmaf(wv.z,v1.z, fmaf(wv.w,v1.w, a1))));
        a2 = fmaf(wv.x,v2.x, fmaf(wv.y,v2.y, fmaf(wv.z,v2.z, fmaf(wv.w,v2.w, a2))));
        a3 = fmaf(wv.x,v3.x, fmaf(wv.y,v3.y, fmaf(wv.z,v3.z, fmaf(wv.w,v3.w, a3))));
    }
    const int b0 = bg*8 + h*4;
    h2[(size_t)(b0+0)*CC2 + col] = fmaxf(a0, 0.f);
    h2[(size_t)(b0+1)*CC2 + col] = fmaxf(a1, 0.f);
    h2[(size_t)(b0+2)*CC2 + col] = fmaxf(a2, 0.f);
    h2[(size_t)(b0+3)*CC2 + col] = fmaxf(a3, 0.f);
}

__global__ __launch_bounds__(256) void k_out(
    const float* __restrict__ h2, const float* __restrict__ W3,
    const float* __restrict__ b3, float* __restrict__ out)
{   // grid 4: 64 batches per block, 4 lanes per batch
    const int t = threadIdx.x;
    const int b = blockIdx.x*64 + (t >> 2);
    const int q = t & 3;
    const float4* h4 = (const float4*)(h2 + (size_t)b*256);
    const float4* w4 = (const float4*)W3;
    float acc = 0.f;
    #pragma unroll
    for (int i = 0; i < 16; ++i) {
        const int f = q + i*4;
        const float4 hh = h4[f], ww = w4[f];
        acc = fmaf(hh.x,ww.x, fmaf(hh.y,ww.y, fmaf(hh.z,ww.z, fmaf(hh.w,ww.w, acc))));
    }
    acc += __shfl_xor(acc, 1, 4);
    acc += __shfl_xor(acc, 2, 4);
    if (q == 0) out[b] = 1.f / (1.f + expf(-(acc + b3[0])));
}

// ---------------- fallback (round-1 pipeline) for small ws ----------------
__global__ __launch_bounds__(256) void fb_path_kernel(
    const int* __restrict__ start_ids, const int* __restrict__ end_ids,
    const int* __restrict__ module_ids,
    const float* __restrict__ embed, const float* __restrict__ W,
    const float* __restrict__ bvec, float* __restrict__ feat_ws)
{
    const int bp = blockIdx.x, t = threadIdx.x;
    __shared__ float bufx[2][EE];
    __shared__ float bufy[2][EE];
    const int sid = start_ids[bp], eid = end_ids[bp];
    if (t < EE) bufx[0][t]      = embed[(size_t)sid*EE + t];
    else        bufy[0][t - EE] = embed[(size_t)eid*EE + (t - EE)];
    __syncthreads();
    const int o = t & (EE - 1);
    int cur = 0;
    for (int l = 0; l < LL; ++l) {
        const int mid = module_ids[bp*LL + l];
        const float*  vin  = (t < EE) ? bufx[cur] : bufy[cur];
        const float4* v4   = (const float4*)vin;
        const float4* wrow = (const float4*)(W + ((size_t)mid*EE + o)*EE);
        float acc = bvec[(size_t)mid*EE + o];
        #pragma unroll 8
        for (int k = 0; k < EE/4; ++k) {
            const float4 wv = wrow[k]; const float4 v = v4[k];
            acc = fmaf(wv.x,v.x, fmaf(wv.y,v.y, fmaf(wv.z,v.z, fmaf(wv.w,v.w, acc))));
        }
        if (t < EE) bufx[1-cur][o] = acc; else bufy[1-cur][o] = acc;
        __syncthreads();
        cur = 1 - cur;
    }
    feat_ws[(size_t)bp*(2*EE) + t] = (t < EE) ? bufx[cur][t] : bufy[cur][t - EE];
}

__global__ __launch_bounds__(256) void fb_mlp_kernel(
    const int* __restrict__ counts, const float* __restrict__ feat_ws,
    const float* __restrict__ W1, const float* __restrict__ b1,
    const float* __restrict__ W2, const float* __restrict__ b2,
    const float* __restrict__ W3, const float* __restrict__ b3,
    float* __restrict__ out)
{
    const int t = threadIdx.x, b0 = blockIdx.x*8;
    __shared__ float pooled[8][2*EE];
    __shared__ float h1s[8][CC1];
    __shared__ float h2s[8][CC2];
    for (int j = 0; j < 8; ++j) {
        const int b = b0 + j;
        float acc = 0.f, csum = 0.f;
        #pragma unroll
        for (int p = 0; p < PP; ++p) {
            const float cc = (float)counts[b*PP + p];
            csum += cc;
            acc = fmaf(cc, feat_ws[(size_t)(b*PP + p)*(2*EE) + t], acc);
        }
        pooled[j][t] = acc / csum;
    }
    __syncthreads();
    for (int rh = 0; rh < 2; ++rh) {
        const int r = t + rh*256;
        float acc[8]; const float bb = b1[r];
        #pragma unroll
        for (int j = 0; j < 8; ++j) acc[j] = bb;
        const float4* w4 = (const float4*)(W1 + (size_t)r*(2*EE));
        for (int k = 0; k < (2*EE)/4; ++k) {
            const float4 wv = w4[k];
            #pragma unroll
            for (int j = 0; j < 8; ++j) {
                const float4 v = ((const float4*)pooled[j])[k];
                acc[j] = fmaf(wv.x,v.x, fmaf(wv.y,v.y, fmaf(wv.z,v.z, fmaf(wv.w,v.w, acc[j]))));
            }
        }
        #pragma unroll
        for (int j = 0; j < 8; ++j) h1s[j][r] = fmaxf(acc[j], 0.f);
    }
    __syncthreads();
    {
        const int r = t;
        float acc[8]; const float bb = b2[r];
        #pragma unroll
        for (int j = 0; j < 8; ++j) acc[j] = bb;
        const float4* w4 = (const float4*)(W2 + (size_t)r*CC1);
        for (int k = 0; k < CC1/4; ++k) {
            const float4 wv = w4[k];
            #pragma unroll
            for (int j = 0; j < 8; ++j) {
                const float4 v = ((const float4*)h1s[j])[k];
                acc[j] = fmaf(wv.x,v.x, fmaf(wv.y,v.y, fmaf(wv.z,v.z, fmaf(wv.w,v.w, acc[j]))));
            }
        }
        #pragma unroll
        for (int j = 0; j < 8; ++j) h2s[j][r] = fmaxf(acc[j], 0.f);
    }
    __syncthreads();
    const int j = t >> 5, k = t & 31;
    float partial = 0.f;
    #pragma unroll
    for (int m = 0; m < CC2; m += 32)
        partial = fmaf(W3[k + m], h2s[j][k + m], partial);
    #pragma unroll
    for (int s = 16; s >= 1; s >>= 1) partial += __shfl_down(partial, s, 32);
    if (k == 0) out[b0 + j] = 1.f / (1.f + expf(-(partial + b3[0])));
}

// ---------------------------------------------------------------------------
extern "C" void kernel_launch(void* const* d_in, const int* in_sizes, int n_in,
                              void* d_out, int out_size, void* d_ws, size_t ws_size,
                              hipStream_t stream)
{
    const int*   start_ids  = (const int*)d_in[0];
    const int*   end_ids    = (const int*)d_in[1];
    const int*   module_ids = (const int*)d_in[2];
    const int*   counts     = (const int*)d_in[3];
    const float* embed      = (const float*)d_in[4];
    const float* W          = (const float*)d_in[5];
    const float* bvec       = (const float*)d_in[6];
    const float* W1         = (const float*)d_in[7];
    const float* b1         = (const float*)d_in[8];
    const float* W2         = (const float*)d_in[9];
    const float* b2         = (const float*)d_in[10];
    const float* W3         = (const float*)d_in[11];
    const float* b3         = (const float*)d_in[12];
    float* out = (float*)d_out;
    char*  ws  = (char*)d_ws;

    if (ws_size >= (size_t)WS_END) {
        float* state  = (float*)(ws + WS_STATE);
        int*   cnt    = (int*)(ws + WS_CNT);
        int*   offs   = (int*)(ws + WS_OFF);
        int*   curp   = (int*)(ws + WS_CUR);
        int*   lists  = (int*)(ws + WS_LISTS);
        float* pooled = (float*)(ws + WS_POOLED);
        float* h1     = (float*)(ws + WS_H1);
        float* h2     = (float*)(ws + WS_H2);

        k_zero<<<8, 256, 0, stream>>>(cnt);
        k_seed<<<NPATH, 256, 0, stream>>>(start_ids, end_ids, module_ids, embed, state, cnt);
        k_scan<<<LL, NMOD, 0, stream>>>(cnt, offs, curp);
        k_scatter<<<NPATH*LL/256, 256, 0, stream>>>(module_ids, curp, lists);
        for (int l = 0; l < LL; ++l)
            k_step<<<NMOD, 256, 0, stream>>>(l, W, bvec, cnt, offs, lists, state);
        k_pool<<<BB, 256, 0, stream>>>(counts, state, pooled);
        k_h1<<<128, 256, 0, stream>>>(pooled, W1, b1, h1);
        k_h2<<<64, 256, 0, stream>>>(h1, W2, b2, h2);
        k_out<<<4, 256, 0, stream>>>(h2, W3, b3, out);
    } else {
        float* feat_ws = (float*)d_ws;
        fb_path_kernel<<<NPATH, 256, 0, stream>>>(start_ids, end_ids, module_ids,
                                                  embed, W, bvec, feat_ws);
        fb_mlp_kernel<<<BB/8, 256, 0, stream>>>(counts, feat_ws, W1, b1, W2, b2,
                                                W3, b3, out);
    }
}

// Round 4
// 446.950 us; speedup vs baseline: 1.3232x; 1.0109x over previous
//
#include <hip/hip_runtime.h>
#include <math.h>

#define BB 256
#define PP 16
#define LL 4
#define EE 128
#define NPATH (BB*PP)     // 4096
#define NMOD 512
#define CC1 512
#define CC2 256

// ---------------- workspace layout (fast path) ----------------
#define WS_STATE   0                              // [4096][2][128] f32 = 4 MB
#define WS_CNT     (NPATH*2*EE*4)                 // [4][512] int
#define WS_OFF     (WS_CNT  + LL*NMOD*4)          // [4][512] int
#define WS_LISTS   (WS_OFF  + LL*NMOD*4)          // [4][4096] int
#define WS_END     (WS_LISTS + LL*NPATH*4)        // ~4.08 MB

#define FMA4(A, S, Wv) do{ (A).x=fmaf((S),(Wv).x,(A).x); (A).y=fmaf((S),(Wv).y,(A).y); \
                           (A).z=fmaf((S),(Wv).z,(A).z); (A).w=fmaf((S),(Wv).w,(A).w);}while(0)

__device__ __forceinline__ unsigned short f2bf(float f) {
    unsigned u = __float_as_uint(f);
    u = (u + 0x7fffu + ((u >> 16) & 1u)) >> 16;   // round-to-nearest-even
    return (unsigned short)u;
}
__device__ __forceinline__ float bf2f(unsigned short s) {
    return __uint_as_float(((unsigned)s) << 16);
}

// ---------------- bucketing: histogram + scan + scatter, one kernel --------
__global__ __launch_bounds__(512) void k_bucket(
    const int* __restrict__ module_ids, int* __restrict__ cnt_g,
    int* __restrict__ off_g, int* __restrict__ lists)
{   // grid LL=4 (one block per step), 512 threads (one per module id)
    const int l = blockIdx.x, t = threadIdx.x;
    __shared__ int s[NMOD];
    __shared__ int pos[NMOD];
    s[t] = 0;
    __syncthreads();
    int mloc[8];
    #pragma unroll
    for (int j = 0; j < 8; ++j) {
        const int bp = j*512 + t;
        const int m = module_ids[bp*LL + l];
        mloc[j] = m;
        atomicAdd(&s[m], 1);
    }
    __syncthreads();
    const int c = s[t];
    // naive inclusive scan over 512
    for (int d = 1; d < NMOD; d <<= 1) {
        const int v = (t >= d) ? s[t-d] : 0;
        __syncthreads();
        s[t] += v;
        __syncthreads();
    }
    const int excl = s[t] - c;
    cnt_g[l*NMOD + t] = c;
    off_g[l*NMOD + t] = excl;
    pos[t] = excl;
    __syncthreads();
    #pragma unroll
    for (int j = 0; j < 8; ++j) {
        const int p = atomicAdd(&pos[mloc[j]], 1);
        lists[l*NPATH + p] = j*512 + t;
    }
}

// ---------------- seed: gather endpoint embeddings ----------------
__global__ __launch_bounds__(256) void k_seed(
    const int* __restrict__ start_ids, const int* __restrict__ end_ids,
    const float* __restrict__ embed, float* __restrict__ state)
{
    const int bp = blockIdx.x, t = threadIdx.x;
    const int id = (t < EE) ? start_ids[bp] : end_ids[bp];
    state[(size_t)bp*256 + t] = embed[(size_t)id*EE + (t & (EE-1))];
}

// ---------------- grouped per-module matvec step (bf16 W in LDS) ----------
// One block per module. Ws[k][oc] bf16 (32 KB, staged once, transposed);
// 32-row fp32 vector slab (16 KB). Each thread: 4 rows x 4 cols.
// Inner loop: 4 ds_read_b64 (2-way, free) + 4 ds_read_b128 (broadcast)
// per 64 FMAs -> VALU-bound.
__global__ __launch_bounds__(256) void k_step(
    const int l, const float* __restrict__ W, const float* __restrict__ bvec,
    const int* __restrict__ cnt, const int* __restrict__ off,
    const int* __restrict__ lists, float* __restrict__ state)
{
    __shared__ unsigned short Ws[128*128];   // [k][oc] bf16, 32 KB
    __shared__ float vb[32*128];             // [row][k] fp32, 16 KB
    const int m = blockIdx.x, t = threadIdx.x;
    const int n = cnt[l*NMOD + m];
    if (n == 0) return;

    // stage W[m] transposed into Ws (bf16). thread: oc = t&127, kh = t>>7.
    {
        const int oc = t & 127, kh = t >> 7;
        const float4* Wr = (const float4*)(W + ((size_t)m*128 + oc)*128 + kh*64);
        #pragma unroll
        for (int it = 0; it < 16; ++it) {
            const float4 wv = Wr[it];
            const int k0 = kh*64 + it*4;
            Ws[(k0+0)*128 + oc] = f2bf(wv.x);
            Ws[(k0+1)*128 + oc] = f2bf(wv.y);
            Ws[(k0+2)*128 + oc] = f2bf(wv.z);
            Ws[(k0+3)*128 + oc] = f2bf(wv.w);
        }
    }

    const int* lst = lists + l*NPATH + off[l*NMOD + m];
    const int nr = 2*n;                 // rows = (path, x|y)
    const int cg = t & 31;              // cols 4cg..4cg+3
    const int rg = t >> 5;              // rows rg*4..rg*4+3
    const float4 bias4 = ((const float4*)(bvec + (size_t)m*128))[cg];

    for (int base = 0; base < nr; base += 32) {
        __syncthreads();                // Ws ready / prior vb readers done
        #pragma unroll
        for (int it = 0; it < 4; ++it) {
            const int flat = it*256 + t;
            const int row = flat >> 5, c4 = flat & 31;
            float4 v = make_float4(0.f, 0.f, 0.f, 0.f);
            const int r = base + row;
            if (r < nr) {
                const int pv = lst[r >> 1]*2 + (r & 1);
                v = ((const float4*)state)[pv*32 + c4];
            }
            ((float4*)vb)[row*32 + c4] = v;
        }
        __syncthreads();

        float4 acc0 = make_float4(0,0,0,0), acc1 = make_float4(0,0,0,0);
        float4 acc2 = make_float4(0,0,0,0), acc3 = make_float4(0,0,0,0);
        const int r0 = rg*4;
        #pragma unroll 4
        for (int k0 = 0; k0 < 128; k0 += 4) {
            const ushort4 u0 = *(const ushort4*)&Ws[(k0+0)*128 + 4*cg];
            const ushort4 u1 = *(const ushort4*)&Ws[(k0+1)*128 + 4*cg];
            const ushort4 u2 = *(const ushort4*)&Ws[(k0+2)*128 + 4*cg];
            const ushort4 u3 = *(const ushort4*)&Ws[(k0+3)*128 + 4*cg];
            const int q = k0 >> 2;
            const float4 va0 = ((const float4*)vb)[(r0+0)*32 + q];
            const float4 va1 = ((const float4*)vb)[(r0+1)*32 + q];
            const float4 va2 = ((const float4*)vb)[(r0+2)*32 + q];
            const float4 va3 = ((const float4*)vb)[(r0+3)*32 + q];
            const float4 w0 = make_float4(bf2f(u0.x), bf2f(u0.y), bf2f(u0.z), bf2f(u0.w));
            const float4 w1 = make_float4(bf2f(u1.x), bf2f(u1.y), bf2f(u1.z), bf2f(u1.w));
            const float4 w2 = make_float4(bf2f(u2.x), bf2f(u2.y), bf2f(u2.z), bf2f(u2.w));
            const float4 w3 = make_float4(bf2f(u3.x), bf2f(u3.y), bf2f(u3.z), bf2f(u3.w));
            FMA4(acc0, va0.x, w0); FMA4(acc0, va0.y, w1); FMA4(acc0, va0.z, w2); FMA4(acc0, va0.w, w3);
            FMA4(acc1, va1.x, w0); FMA4(acc1, va1.y, w1); FMA4(acc1, va1.z, w2); FMA4(acc1, va1.w, w3);
            FMA4(acc2, va2.x, w0); FMA4(acc2, va2.y, w1); FMA4(acc2, va2.z, w2); FMA4(acc2, va2.w, w3);
            FMA4(acc3, va3.x, w0); FMA4(acc3, va3.y, w1); FMA4(acc3, va3.z, w2); FMA4(acc3, va3.w, w3);
        }
        float4 accs[4] = {acc0, acc1, acc2, acc3};
        #pragma unroll
        for (int i = 0; i < 4; ++i) {
            const int r = base + r0 + i;
            if (r < nr) {
                const int pv = lst[r >> 1]*2 + (r & 1);
                float4 o = make_float4(accs[i].x + bias4.x, accs[i].y + bias4.y,
                                       accs[i].z + bias4.z, accs[i].w + bias4.w);
                ((float4*)state)[pv*32 + cg] = o;
            }
        }
    }
}

// ---------------- fused pooling + full MLP ----------------
// 128 blocks x 256 threads, 2 batch rows per block. Per-batch-row
// independence means no grid syncs; weights stream from L2 (~1 MB/block).
__global__ __launch_bounds__(256) void k_mlp(
    const int* __restrict__ counts, const float* __restrict__ state,
    const float* __restrict__ W1, const float* __restrict__ b1,
    const float* __restrict__ W2, const float* __restrict__ b2,
    const float* __restrict__ W3, const float* __restrict__ b3,
    float* __restrict__ out)
{
    const int t = threadIdx.x;
    const int b0 = blockIdx.x * 2;
    __shared__ float pl[2][256];
    __shared__ float h1s[2][CC1];
    __shared__ float h2s[2][CC2];
    __shared__ float red[256];

    // pooling
    #pragma unroll
    for (int r = 0; r < 2; ++r) {
        const int b = b0 + r;
        float acc = 0.f, cs = 0.f;
        #pragma unroll
        for (int p = 0; p < PP; ++p) {
            const float cc = (float)counts[b*PP + p];
            cs += cc;
            acc = fmaf(cc, state[((size_t)(b*PP + p))*256 + t], acc);
        }
        pl[r][t] = acc / cs;
    }
    __syncthreads();

    // h1: cols t and t+256, both rows
    #pragma unroll
    for (int hh = 0; hh < 2; ++hh) {
        const int col = t + hh*256;
        const float4* w4 = (const float4*)(W1 + (size_t)col*256);
        float a0 = b1[col], a1 = a0;
        for (int q = 0; q < 64; ++q) {
            const float4 wv = w4[q];
            const float4 v0 = ((const float4*)pl[0])[q];
            const float4 v1 = ((const float4*)pl[1])[q];
            a0 = fmaf(wv.x,v0.x, fmaf(wv.y,v0.y, fmaf(wv.z,v0.z, fmaf(wv.w,v0.w, a0))));
            a1 = fmaf(wv.x,v1.x, fmaf(wv.y,v1.y, fmaf(wv.z,v1.z, fmaf(wv.w,v1.w, a1))));
        }
        h1s[0][col] = fmaxf(a0, 0.f);
        h1s[1][col] = fmaxf(a1, 0.f);
    }
    __syncthreads();

    // h2: col t, both rows
    {
        const float4* w4 = (const float4*)(W2 + (size_t)t*512);
        float a0 = b2[t], a1 = a0;
        for (int q = 0; q < 128; ++q) {
            const float4 wv = w4[q];
            const float4 v0 = ((const float4*)h1s[0])[q];
            const float4 v1 = ((const float4*)h1s[1])[q];
            a0 = fmaf(wv.x,v0.x, fmaf(wv.y,v0.y, fmaf(wv.z,v0.z, fmaf(wv.w,v0.w, a0))));
            a1 = fmaf(wv.x,v1.x, fmaf(wv.y,v1.y, fmaf(wv.z,v1.z, fmaf(wv.w,v1.w, a1))));
        }
        h2s[0][t] = fmaxf(a0, 0.f);
        h2s[1][t] = fmaxf(a1, 0.f);
    }
    __syncthreads();

    // out: 128 lanes per row; k = t&127 covers k and k+128
    {
        const int r = t >> 7, k = t & 127;
        red[t] = fmaf(W3[k], h2s[r][k], W3[k+128] * h2s[r][k+128]);
        for (int s = 64; s > 0; s >>= 1) {
            __syncthreads();
            if ((t & 127) < s) red[t] += red[t + s];
        }
        __syncthreads();
        if ((t & 127) == 0)
            out[b0 + r] = 1.f / (1.f + expf(-(red[t] + b3[0])));
    }
}

// ---------------- fallback (round-1 pipeline) for small ws ----------------
__global__ __launch_bounds__(256) void fb_path_kernel(
    const int* __restrict__ start_ids, const int* __restrict__ end_ids,
    const int* __restrict__ module_ids,
    const float* __restrict__ embed, const float* __restrict__ W,
    const float* __restrict__ bvec, float* __restrict__ feat_ws)
{
    const int bp = blockIdx.x, t = threadIdx.x;
    __shared__ float bufx[2][EE];
    __shared__ float bufy[2][EE];
    const int sid = start_ids[bp], eid = end_ids[bp];
    if (t < EE) bufx[0][t]      = embed[(size_t)sid*EE + t];
    else        bufy[0][t - EE] = embed[(size_t)eid*EE + (t - EE)];
    __syncthreads();
    const int o = t & (EE - 1);
    int cur = 0;
    for (int l = 0; l < LL; ++l) {
        const int mid = module_ids[bp*LL + l];
        const float*  vin  = (t < EE) ? bufx[cur] : bufy[cur];
        const float4* v4   = (const float4*)vin;
        const float4* wrow = (const float4*)(W + ((size_t)mid*EE + o)*EE);
        float acc = bvec[(size_t)mid*EE + o];
        #pragma unroll 8
        for (int k = 0; k < EE/4; ++k) {
            const float4 wv = wrow[k]; const float4 v = v4[k];
            acc = fmaf(wv.x,v.x, fmaf(wv.y,v.y, fmaf(wv.z,v.z, fmaf(wv.w,v.w, acc))));
        }
        if (t < EE) bufx[1-cur][o] = acc; else bufy[1-cur][o] = acc;
        __syncthreads();
        cur = 1 - cur;
    }
    feat_ws[(size_t)bp*(2*EE) + t] = (t < EE) ? bufx[cur][t] : bufy[cur][t - EE];
}

__global__ __launch_bounds__(256) void fb_mlp_kernel(
    const int* __restrict__ counts, const float* __restrict__ feat_ws,
    const float* __restrict__ W1, const float* __restrict__ b1,
    const float* __restrict__ W2, const float* __restrict__ b2,
    const float* __restrict__ W3, const float* __restrict__ b3,
    float* __restrict__ out)
{
    const int t = threadIdx.x, b0 = blockIdx.x*8;
    __shared__ float pooled[8][2*EE];
    __shared__ float h1s[8][CC1];
    __shared__ float h2s[8][CC2];
    for (int j = 0; j < 8; ++j) {
        const int b = b0 + j;
        float acc = 0.f, csum = 0.f;
        #pragma unroll
        for (int p = 0; p < PP; ++p) {
            const float cc = (float)counts[b*PP + p];
            csum += cc;
            acc = fmaf(cc, feat_ws[(size_t)(b*PP + p)*(2*EE) + t], acc);
        }
        pooled[j][t] = acc / csum;
    }
    __syncthreads();
    for (int rh = 0; rh < 2; ++rh) {
        const int r = t + rh*256;
        float acc[8]; const float bb = b1[r];
        #pragma unroll
        for (int j = 0; j < 8; ++j) acc[j] = bb;
        const float4* w4 = (const float4*)(W1 + (size_t)r*(2*EE));
        for (int k = 0; k < (2*EE)/4; ++k) {
            const float4 wv = w4[k];
            #pragma unroll
            for (int j = 0; j < 8; ++j) {
                const float4 v = ((const float4*)pooled[j])[k];
                acc[j] = fmaf(wv.x,v.x, fmaf(wv.y,v.y, fmaf(wv.z,v.z, fmaf(wv.w,v.w, acc[j]))));
            }
        }
        #pragma unroll
        for (int j = 0; j < 8; ++j) h1s[j][r] = fmaxf(acc[j], 0.f);
    }
    __syncthreads();
    {
        const int r = t;
        float acc[8]; const float bb = b2[r];
        #pragma unroll
        for (int j = 0; j < 8; ++j) acc[j] = bb;
        const float4* w4 = (const float4*)(W2 + (size_t)r*CC1);
        for (int k = 0; k < CC1/4; ++k) {
            const float4 wv = w4[k];
            #pragma unroll
            for (int j = 0; j < 8; ++j) {
                const float4 v = ((const float4*)h1s[j])[k];
                acc[j] = fmaf(wv.x,v.x, fmaf(wv.y,v.y, fmaf(wv.z,v.z, fmaf(wv.w,v.w, acc[j]))));
            }
        }
        #pragma unroll
        for (int j = 0; j < 8; ++j) h2s[j][r] = fmaxf(acc[j], 0.f);
    }
    __syncthreads();
    const int j = t >> 5, k = t & 31;
    float partial = 0.f;
    #pragma unroll
    for (int m = 0; m < CC2; m += 32)
        partial = fmaf(W3[k + m], h2s[j][k + m], partial);
    #pragma unroll
    for (int s = 16; s >= 1; s >>= 1) partial += __shfl_down(partial, s, 32);
    if (k == 0) out[b0 + j] = 1.f / (1.f + expf(-(partial + b3[0])));
}

// ---------------------------------------------------------------------------
extern "C" void kernel_launch(void* const* d_in, const int* in_sizes, int n_in,
                              void* d_out, int out_size, void* d_ws, size_t ws_size,
                              hipStream_t stream)
{
    const int*   start_ids  = (const int*)d_in[0];
    const int*   end_ids    = (const int*)d_in[1];
    const int*   module_ids = (const int*)d_in[2];
    const int*   counts     = (const int*)d_in[3];
    const float* embed      = (const float*)d_in[4];
    const float* W          = (const float*)d_in[5];
    const float* bvec       = (const float*)d_in[6];
    const float* W1         = (const float*)d_in[7];
    const float* b1         = (const float*)d_in[8];
    const float* W2         = (const float*)d_in[9];
    const float* b2         = (const float*)d_in[10];
    const float* W3         = (const float*)d_in[11];
    const float* b3         = (const float*)d_in[12];
    float* out = (float*)d_out;
    char*  ws  = (char*)d_ws;

    if (ws_size >= (size_t)WS_END) {
        float* state = (float*)(ws + WS_STATE);
        int*   cnt   = (int*)(ws + WS_CNT);
        int*   offs  = (int*)(ws + WS_OFF);
        int*   lists = (int*)(ws + WS_LISTS);

        k_bucket<<<LL, 512, 0, stream>>>(module_ids, cnt, offs, lists);
        k_seed<<<NPATH, 256, 0, stream>>>(start_ids, end_ids, embed, state);
        for (int l = 0; l < LL; ++l)
            k_step<<<NMOD, 256, 0, stream>>>(l, W, bvec, cnt, offs, lists, state);
        k_mlp<<<BB/2, 256, 0, stream>>>(counts, state, W1, b1, W2, b2, W3, b3, out);
    } else {
        float* feat_ws = (float*)d_ws;
        fb_path_kernel<<<NPATH, 256, 0, stream>>>(start_ids, end_ids, module_ids,
                                                  embed, W, bvec, feat_ws);
        fb_mlp_kernel<<<BB/8, 256, 0, stream>>>(counts, feat_ws, W1, b1, W2, b2,
                                                W3, b3, out);
    }
}